// Round 1
// baseline (2955.381 us; speedup 1.0000x reference)
//
#include <hip/hip_runtime.h>

// ---------------------------------------------------------------------------
// DomainGeneralisationBN (SPD batchnorm) — all-fp32, matmul-only formulation.
//   sqrt/invsqrt : coupled Newton-Schulz (Frobenius-scaled), D=4 matrices only
//   logm         : log(P) = 2*atanh(S), S=(P-I)(P+I)^-1 ; inverse via NS with
//                  quadratic init tuned to eigs(P+I) in [1.2, 6.5]
//   expm / X^p   : Taylor-Horner on S/2 then square
// One 32x32 matrix per wave; operands staged in LDS with stride-36 padding
// (conflict-free broadcast b128 reads); each lane owns a 4x4 block of C.
// L = logm(Xc) is stashed in d_out between K5 and K7 (read-then-overwrite).
// ---------------------------------------------------------------------------

#define LN  36
#define MSZ (32 * LN)

// workspace layout (float offsets)
#define WS_G0SUM 0
#define WS_GTSUM 4096
#define WS_VAR   8192
#define WS_CNT   8196
#define WS_P     8200
#define WS_G0SQ  8208
#define WS_G0ISQ 12304
#define WS_GISQ  16400
#define WS_BSQ   20496
#define WS_ZERO  8208   // floats to zero each launch (sums + var)

// inverse init constants: eigs(M) in [a,b]=[1.2,6.5]:
//   beta = -2/(a*b + ((a+b)/2)^2), alpha = -beta*(a+b)  -> rho0 ~= 0.31
#define INV_AL 0.6807382f
#define INV_BE (-0.0884076f)

__device__ __forceinline__ float wsum(float v) {
#pragma unroll
  for (int o = 32; o > 0; o >>= 1) v += __shfl_xor(v, o, 64);
  return v;
}

__device__ __forceinline__ void zero16(float c[16]) {
#pragma unroll
  for (int i = 0; i < 16; ++i) c[i] = 0.f;
}

__device__ __forceinline__ void addI(float c[16], float v, int bi, int bj) {
  if (bi == bj) { c[0] += v; c[5] += v; c[10] += v; c[15] += v; }
}

// c = (A + diag*I) * B.  A in col-form LDS (A[k*LN+i] = A[i][k]),
// B in row-form LDS (B[k*LN+j] = B[k][j]).  Lane (bi,bj) owns C[4bi..][4bj..].
__device__ __forceinline__ void mm_core(const float* A, const float* B, float c[16],
                                        int bi4, int bj4, int diag) {
  zero16(c);
#pragma unroll 4
  for (int k = 0; k < 32; ++k) {
    float4 a = *(const float4*)(A + k * LN + bi4);
    float4 b = *(const float4*)(B + k * LN + bj4);
    if (diag != 0) {
      const float dg = (float)diag;
      if (k == bi4    ) a.x += dg;
      if (k == bi4 + 1) a.y += dg;
      if (k == bi4 + 2) a.z += dg;
      if (k == bi4 + 3) a.w += dg;
    }
    c[0] = fmaf(a.x, b.x, c[0]);  c[1] = fmaf(a.x, b.y, c[1]);
    c[2] = fmaf(a.x, b.z, c[2]);  c[3] = fmaf(a.x, b.w, c[3]);
    c[4] = fmaf(a.y, b.x, c[4]);  c[5] = fmaf(a.y, b.y, c[5]);
    c[6] = fmaf(a.y, b.z, c[6]);  c[7] = fmaf(a.y, b.w, c[7]);
    c[8] = fmaf(a.z, b.x, c[8]);  c[9] = fmaf(a.z, b.y, c[9]);
    c[10]= fmaf(a.z, b.z, c[10]); c[11]= fmaf(a.z, b.w, c[11]);
    c[12]= fmaf(a.w, b.x, c[12]); c[13]= fmaf(a.w, b.y, c[13]);
    c[14]= fmaf(a.w, b.z, c[14]); c[15]= fmaf(a.w, b.w, c[15]);
  }
}

// write c-regs as row-form (usable as RIGHT operand, or LEFT if symmetric)
__device__ __forceinline__ void st_row(float* buf, const float c[16], int bi4, int bj4) {
#pragma unroll
  for (int di = 0; di < 4; ++di) {
    float4 v = make_float4(c[di*4+0], c[di*4+1], c[di*4+2], c[di*4+3]);
    *(float4*)(buf + (bi4 + di) * LN + bj4) = v;
  }
}

// write c-regs as col-form (for use as LEFT operand of next mm)
__device__ __forceinline__ void st_col(float* buf, const float c[16], int bi4, int bj4) {
#pragma unroll
  for (int dj = 0; dj < 4; ++dj) {
    float4 v = make_float4(c[0*4+dj], c[1*4+dj], c[2*4+dj], c[3*4+dj]);
    *(float4*)(buf + (bj4 + dj) * LN + bi4) = v;
  }
}

// global row-major 32x32 <-> c-regs
__device__ __forceinline__ void ldg_mat(const float* __restrict__ g, float c[16],
                                        int bi4, int bj4) {
#pragma unroll
  for (int di = 0; di < 4; ++di) {
    float4 v = *(const float4*)(g + (bi4 + di) * 32 + bj4);
    c[di*4+0] = v.x; c[di*4+1] = v.y; c[di*4+2] = v.z; c[di*4+3] = v.w;
  }
}
__device__ __forceinline__ void stg_mat(float* __restrict__ g, const float c[16],
                                        int bi4, int bj4, float s) {
#pragma unroll
  for (int di = 0; di < 4; ++di) {
    float4 v = make_float4(c[di*4+0]*s, c[di*4+1]*s, c[di*4+2]*s, c[di*4+3]*s);
    *(float4*)(g + (bi4 + di) * 32 + bj4) = v;
  }
}

// global row-major 1024 floats -> LDS row-form (scaled)
__device__ __forceinline__ void g2l(const float* __restrict__ g, float* buf,
                                    int lane, float s) {
#pragma unroll
  for (int u = 0; u < 4; ++u) {
    int e = lane * 16 + u * 4;
    float4 v = *(const float4*)(g + e);
    v.x *= s; v.y *= s; v.z *= s; v.w *= s;
    *(float4*)(buf + (e >> 5) * LN + (e & 31)) = v;
  }
}

// coupled Newton-Schulz: Ysq = sqrt(A), Zis = invsqrt(A); A SPD in c-regs.
__device__ __forceinline__ void wave_sqrtinv(const float A[16], float Ysq[16], float Zis[16],
                                             float* YB, float* ZB, float* TB,
                                             int bi4, int bj4, int bi, int bj) {
  float ss = 0.f;
#pragma unroll
  for (int i = 0; i < 16; ++i) ss += A[i] * A[i];
  const float th = sqrtf(wsum(ss));
  const float inv = 1.f / th;
  float Y[16], Z[16];
#pragma unroll
  for (int i = 0; i < 16; ++i) Y[i] = A[i] * inv;
  zero16(Z); addI(Z, 1.f, bi, bj);
  st_row(YB, Y, bi4, bj4);
  st_row(ZB, Z, bi4, bj4);
  for (int it = 0; it < 13; ++it) {
    float W[16], T[16];
    mm_core(ZB, YB, W, bi4, bj4, 0);        // W = Z*Y
#pragma unroll
    for (int i = 0; i < 16; ++i) T[i] = -0.5f * W[i];
    addI(T, 1.5f, bi, bj);                   // T = (3I - ZY)/2
    st_row(TB, T, bi4, bj4);
    mm_core(YB, TB, Y, bi4, bj4, 0);         // Y' = Y*T
    mm_core(TB, ZB, Z, bi4, bj4, 0);         // Z' = T*Z
    st_row(YB, Y, bi4, bj4);
    st_row(ZB, Z, bi4, bj4);
  }
  const float sth = sqrtf(th), isth = 1.f / sth;
#pragma unroll
  for (int i = 0; i < 16; ++i) { Ysq[i] = Y[i] * sth; Zis[i] = Z[i] * isth; }
}

// L = log(P), P SPD with eigs in ~[0.2, 5.5].  On entry D1 holds P (row-form,
// symmetric) and Preg holds P in c-regs.  Trashes D1,D2,D3.
__device__ __forceinline__ void wave_logm(float* D1, float* D2, float* D3,
                                          const float Preg[16], float L[16],
                                          int bi4, int bj4, int bi, int bj) {
  // --- Minv = (P+I)^-1 via NS, init X0 = AL*I + BE*(P+I) ---
  float P2[16];
  mm_core(D1, D1, P2, bi4, bj4, 0);                       // P^2
  float U[16];
#pragma unroll
  for (int i = 0; i < 16; ++i) U[i] = -((INV_AL + 2.f*INV_BE) * Preg[i] + INV_BE * P2[i]);
  addI(U, 2.f - (INV_AL + INV_BE), bi, bj);               // U = 2I - M*X0
  st_row(D2, U, bi4, bj4);
  float Xk[16];
  mm_core(D1, D2, Xk, bi4, bj4, 0);                       // P*U
#pragma unroll
  for (int i = 0; i < 16; ++i) Xk[i] = (INV_AL + INV_BE) * U[i] + INV_BE * Xk[i];
  st_row(D2, Xk, bi4, bj4);                               // X1
  for (int it = 0; it < 3; ++it) {
    float T[16], XT_[16];
    mm_core(D1, D2, T, bi4, bj4, +1);                     // T = (P+I)*Xk
    st_row(D3, T, bi4, bj4);
    mm_core(D2, D3, XT_, bi4, bj4, 0);                    // Xk*T
#pragma unroll
    for (int i = 0; i < 16; ++i) Xk[i] = 2.f * Xk[i] - XT_[i];
    st_row(D2, Xk, bi4, bj4);
  }
  // --- S = (P - I) * Minv ; atanh series, 12 odd terms ---
  float S[16];
  mm_core(D1, D2, S, bi4, bj4, -1);
  st_row(D3, S, bi4, bj4);
  float S2[16];
  mm_core(D3, D3, S2, bi4, bj4, 0);
  st_row(D1, S2, bi4, bj4);
  float H[16];
  zero16(H); addI(H, 1.f / 23.f, bi, bj);
  st_row(D2, H, bi4, bj4);
  for (int j = 10; j >= 0; --j) {
    mm_core(D1, D2, H, bi4, bj4, 0);                      // H = S2*H
    addI(H, 1.f / (float)(2 * j + 1), bi, bj);
    st_row(D2, H, bi4, bj4);
  }
  mm_core(D3, D2, L, bi4, bj4, 0);                        // S*H
#pragma unroll
  for (int i = 0; i < 16; ++i) L[i] *= 2.f;
}

// ------------------------------- kernels -----------------------------------

__global__ __launch_bounds__(64) void k1_g0sum(const float* __restrict__ X,
                                               const int* __restrict__ ds,
                                               float* __restrict__ ws, int q) {
  const int n = blockIdx.x, lane = threadIdx.x;
  const int d = ds[n];
  float acc[16];
  zero16(acc);
  const float* base = X + (size_t)n * q * 1024 + lane * 16;
#pragma unroll 4
  for (int j = 0; j < 16; ++j) {
    const float* g = base + (size_t)j * 1024;
#pragma unroll
    for (int u = 0; u < 4; ++u) {
      float4 v = *(const float4*)(g + u * 4);
      acc[u*4+0] += v.x; acc[u*4+1] += v.y; acc[u*4+2] += v.z; acc[u*4+3] += v.w;
    }
  }
  float* dst = ws + WS_G0SUM + d * 1024 + lane * 16;
#pragma unroll
  for (int i = 0; i < 16; ++i) atomicAdd(dst + i, acc[i]);
}

__global__ __launch_bounds__(64) void k2_g0funcs(float* __restrict__ ws,
                                                 const int* __restrict__ ds,
                                                 const float* __restrict__ B,
                                                 int N, int q) {
  __shared__ float D1[MSZ], D2[MSZ], D3[MSZ];
  const int d = blockIdx.x, lane = threadIdx.x;
  const int bi = lane >> 3, bj = lane & 7, bi4 = bi * 4, bj4 = bj * 4;
  int cnt = 0;
  for (int i = lane; i < N; i += 64) cnt += (ds[i] == d) ? 1 : 0;
  const float cntf = wsum((float)cnt);
  if (lane == 0) ws[WS_CNT + d] = cntf;
  float A[16], Y[16], Z[16];
  ldg_mat(ws + WS_G0SUM + d * 1024, A, bi4, bj4);
  const float s = 1.f / ((float)q * cntf);
#pragma unroll
  for (int i = 0; i < 16; ++i) A[i] *= s;
  wave_sqrtinv(A, Y, Z, D1, D2, D3, bi4, bj4, bi, bj);
  stg_mat(ws + WS_G0SQ  + d * 1024, Y, bi4, bj4, 1.f);
  stg_mat(ws + WS_G0ISQ + d * 1024, Z, bi4, bj4, 1.f);
  ldg_mat(B + d * 1024, A, bi4, bj4);
  wave_sqrtinv(A, Y, Z, D1, D2, D3, bi4, bj4, bi, bj);
  stg_mat(ws + WS_BSQ + d * 1024, Y, bi4, bj4, 1.f);
}

__global__ __launch_bounds__(128) void k3_gt(const float* __restrict__ X,
                                             const int* __restrict__ ds,
                                             float* __restrict__ ws, int q) {
  __shared__ float GiB[MSZ], GsB[MSZ], DYN[2][3][MSZ];
  const int n = blockIdx.x, tid = threadIdx.x;
  const int w = tid >> 6, lane = tid & 63;
  const int bi = lane >> 3, bj = lane & 7, bi4 = bi * 4, bj4 = bj * 4;
  const int d = ds[n];
  if (w == 0) g2l(ws + WS_G0ISQ + d * 1024, GiB, lane, 1.f);
  else        g2l(ws + WS_G0SQ  + d * 1024, GsB, lane, 1.f);
  __syncthreads();
  float* D1 = DYN[w][0]; float* D2 = DYN[w][1]; float* D3 = DYN[w][2];
  float acc[16];
  zero16(acc);
  const int half = q >> 1;
  for (int j = 0; j < half; ++j) {
    const size_t m = (size_t)n * q + (size_t)w * half + j;
    g2l(X + m * 1024, D1, lane, 1.f);
    float t[16], P[16], L[16];
    mm_core(GiB, D1, t, bi4, bj4, 0);  st_col(D2, t, bi4, bj4);   // Gi*X
    mm_core(D2, GiB, P, bi4, bj4, 0);  st_row(D1, P, bi4, bj4);   // inner
    wave_logm(D1, D2, D3, P, L, bi4, bj4, bi, bj);
    st_row(D2, L, bi4, bj4);
    mm_core(GsB, D2, t, bi4, bj4, 0);  st_col(D3, t, bi4, bj4);   // Gs*L
    mm_core(D3, GsB, t, bi4, bj4, 0);                             // XT
#pragma unroll
    for (int i = 0; i < 16; ++i) acc[i] += t[i];
  }
  float* dst = ws + WS_GTSUM + d * 1024;
#pragma unroll
  for (int di = 0; di < 4; ++di)
#pragma unroll
    for (int dj = 0; dj < 4; ++dj)
      atomicAdd(dst + (bi4 + di) * 32 + bj4 + dj, acc[di * 4 + dj]);
}

__global__ __launch_bounds__(64) void k4_mean(float* __restrict__ ws, int q) {
  __shared__ float GB[MSZ], D1[MSZ], D2[MSZ], D3[MSZ];
  const int d = blockIdx.x, lane = threadIdx.x;
  const int bi = lane >> 3, bj = lane & 7, bi4 = bi * 4, bj4 = bj * 4;
  const float cntf = ws[WS_CNT + d];
  float c[16], t[16];
  ldg_mat(ws + WS_G0ISQ + d * 1024, c, bi4, bj4); st_row(GB, c, bi4, bj4);
  ldg_mat(ws + WS_GTSUM + d * 1024, c, bi4, bj4);
  const float s = 1.f / ((float)q * cntf);
#pragma unroll
  for (int i = 0; i < 16; ++i) c[i] *= s;                        // GT
  st_row(D1, c, bi4, bj4);
  mm_core(GB, D1, t, bi4, bj4, 0); st_col(D2, t, bi4, bj4);
  mm_core(D2, GB, t, bi4, bj4, 0); st_row(D1, t, bi4, bj4);      // E = Gi*GT*Gi
  float H[16];
  zero16(H); addI(H, 2.7557319e-7f, bi, bj);                     // 1/10!
  st_row(D2, H, bi4, bj4);
  float ck = 2.7557319e-7f;
  for (int kk = 9; kk >= 0; --kk) {
    ck *= (float)(kk + 1);
    mm_core(D1, D2, H, bi4, bj4, 0);
    addI(H, ck, bi, bj);
    st_row(D2, H, bi4, bj4);
  }                                                              // H = exp(E)
  ldg_mat(ws + WS_G0SQ + d * 1024, c, bi4, bj4); st_row(GB, c, bi4, bj4);
  st_row(D1, H, bi4, bj4);
  mm_core(GB, D1, t, bi4, bj4, 0); st_col(D2, t, bi4, bj4);
  mm_core(D2, GB, t, bi4, bj4, 0);                               // G
  float Y[16], Z[16];
  wave_sqrtinv(t, Y, Z, D1, D2, D3, bi4, bj4, bi, bj);
  stg_mat(ws + WS_GISQ + d * 1024, Z, bi4, bj4, 1.f);
}

__global__ __launch_bounds__(128) void k5_logxc(const float* __restrict__ X,
                                                const int* __restrict__ ds,
                                                float* __restrict__ ws,
                                                float* __restrict__ Lout, int q) {
  __shared__ float GiB[MSZ], DYN[2][3][MSZ];
  const int n = blockIdx.x, tid = threadIdx.x;
  const int w = tid >> 6, lane = tid & 63;
  const int bi = lane >> 3, bj = lane & 7, bi4 = bi * 4, bj4 = bj * 4;
  const int d = ds[n];
  if (w == 0) g2l(ws + WS_GISQ + d * 1024, GiB, lane, 1.f);
  __syncthreads();
  float* D1 = DYN[w][0]; float* D2 = DYN[w][1]; float* D3 = DYN[w][2];
  float vacc = 0.f;
  const int half = q >> 1;
  for (int j = 0; j < half; ++j) {
    const size_t m = (size_t)n * q + (size_t)w * half + j;
    g2l(X + m * 1024, D1, lane, 1.f);
    float t[16], P[16], L[16];
    mm_core(GiB, D1, t, bi4, bj4, 0);  st_col(D2, t, bi4, bj4);
    mm_core(D2, GiB, P, bi4, bj4, 0);  st_row(D1, P, bi4, bj4);  // Xc
    wave_logm(D1, D2, D3, P, L, bi4, bj4, bi, bj);
    float sq = 0.f;
#pragma unroll
    for (int i = 0; i < 16; ++i) sq += L[i] * L[i];
    vacc += sq;
    stg_mat(Lout + m * 1024, L, bi4, bj4, 1.f);
  }
  vacc = wsum(vacc);
  if (lane == 0) atomicAdd(ws + WS_VAR + d, vacc);
}

__global__ __launch_bounds__(64) void k6_p(float* __restrict__ ws, int q, int D) {
  const int lane = threadIdx.x;
  if (lane < D) {
    const float cntf = ws[WS_CNT + lane];
    const float var = ws[WS_VAR + lane] / ((float)q * cntf);
    ws[WS_P + lane] = sqrtf(1.f / (var + 1e-5f));
  }
}

__global__ __launch_bounds__(128) void k7_out(const int* __restrict__ ds,
                                              const float* __restrict__ ws,
                                              const float* __restrict__ R,
                                              float* __restrict__ io, int q) {
  __shared__ float RcB[MSZ], BsB[MSZ], DYN[2][2][MSZ];
  const int n = blockIdx.x, tid = threadIdx.x;
  const int w = tid >> 6, lane = tid & 63;
  const int bi = lane >> 3, bj = lane & 7, bi4 = bi * 4, bj4 = bj * 4;
  const int d = ds[n];
  if (w == 0) { float c[16]; ldg_mat(R + d * 1024, c, bi4, bj4);            st_col(RcB, c, bi4, bj4); }
  else        { float c[16]; ldg_mat(ws + WS_BSQ + d * 1024, c, bi4, bj4);  st_row(BsB, c, bi4, bj4); }
  __syncthreads();
  const float ph = 0.5f * ws[WS_P + d];
  float* D1 = DYN[w][0]; float* D2 = DYN[w][1];
  const int half = q >> 1;
  for (int j = 0; j < half; ++j) {
    const size_t m = (size_t)n * q + (size_t)w * half + j;
    g2l(io + m * 1024, D1, lane, ph);                       // Sh = (p/2)*L
    float H[16], t[16];
    zero16(H); addI(H, 2.0876757e-9f, bi, bj);              // 1/12!
    st_row(D2, H, bi4, bj4);
    float ck = 2.0876757e-9f;
    for (int kk = 11; kk >= 0; --kk) {
      ck *= (float)(kk + 1);
      mm_core(D1, D2, H, bi4, bj4, 0);
      addI(H, ck, bi, bj);
      st_row(D2, H, bi4, bj4);
    }                                                       // H = exp(Sh)
    mm_core(D2, D2, t, bi4, bj4, 0);  st_row(D1, t, bi4, bj4);   // Xp = H*H
    mm_core(RcB, D1, t, bi4, bj4, 0); st_col(D2, t, bi4, bj4);   // R*Xp
    mm_core(D2, RcB, t, bi4, bj4, 0); st_row(D1, t, bi4, bj4);   // Xr = (R Xp) R^T
    mm_core(BsB, D1, t, bi4, bj4, 0); st_col(D2, t, bi4, bj4);   // Bs*Xr
    mm_core(D2, BsB, t, bi4, bj4, 0);                            // out
    stg_mat(io + m * 1024, t, bi4, bj4, 1.f);
  }
}

// ------------------------------- launcher ----------------------------------

extern "C" void kernel_launch(void* const* d_in, const int* in_sizes, int n_in,
                              void* d_out, int out_size, void* d_ws, size_t ws_size,
                              hipStream_t stream) {
  const float* X  = (const float*)d_in[0];
  const int*   ds = (const int*)d_in[1];
  const float* R  = (const float*)d_in[2];
  const float* B  = (const float*)d_in[3];
  float* out = (float*)d_out;
  float* ws  = (float*)d_ws;
  const int N = in_sizes[1];                 // 2048
  const int q = in_sizes[0] / (N * 1024);    // 16
  const int D = in_sizes[2] / 1024;          // 4
  (void)n_in; (void)out_size; (void)ws_size;

  hipMemsetAsync(d_ws, 0, WS_ZERO * sizeof(float), stream);
  k1_g0sum  <<<dim3(N), dim3(64),  0, stream>>>(X, ds, ws, q);
  k2_g0funcs<<<dim3(D), dim3(64),  0, stream>>>(ws, ds, B, N, q);
  k3_gt     <<<dim3(N), dim3(128), 0, stream>>>(X, ds, ws, q);
  k4_mean   <<<dim3(D), dim3(64),  0, stream>>>(ws, q);
  k5_logxc  <<<dim3(N), dim3(128), 0, stream>>>(X, ds, ws, out, q);
  k6_p      <<<dim3(1), dim3(64),  0, stream>>>(ws, q, D);
  k7_out    <<<dim3(N), dim3(128), 0, stream>>>(ds, ws, R, out, q);
}

// Round 2
// 2522.339 us; speedup vs baseline: 1.1717x; 1.1717x over previous
//
#include <hip/hip_runtime.h>

// ---------------------------------------------------------------------------
// DomainGeneralisationBN (SPD batchnorm) — all-fp32, matmul-only formulation.
// R2: 2-LDS-buffer logm (register-carried NS iterate), generalized
//     mm_gen = sc*(A+da I)(B+db I) with rank-correction (no inner-loop masks),
//     trimmed series (NS-inv 3 iters on [1.15,8] Chebyshev init, Gregory 9
//     terms, exp 10 terms).  Occupancy: k5 14 waves/CU, k3/k7 10 waves/CU.
// One 32x32 matrix per wave; LDS stride-36 padding; lane owns 4x4 C-block.
// L = logm(Xc) stashed in d_out between K5 and K7.
// ---------------------------------------------------------------------------

#define LN  36
#define MSZ (32 * LN)

// workspace layout (float offsets)
#define WS_G0SUM 0
#define WS_GTSUM 4096
#define WS_VAR   8192
#define WS_CNT   8196
#define WS_P     8200
#define WS_G0SQ  8208
#define WS_G0ISQ 12304
#define WS_GISQ  16400
#define WS_BSQ   20496
#define WS_ZERO  8208

// (P+I)^-1 NS init, Chebyshev-optimal linear on eigs(M) in [1.15, 8]:
//   X0 = AL*I + BE*M = BE*(P + C0*I),  rho0 = 0.3893, 3 doublings -> 2.8e-7
#define LOG_BE (-0.0663776f)
#define LOG_C0 (-8.149997f)

__device__ __forceinline__ float wsum(float v) {
#pragma unroll
  for (int o = 32; o > 0; o >>= 1) v += __shfl_xor(v, o, 64);
  return v;
}

__device__ __forceinline__ void zero16(float c[16]) {
#pragma unroll
  for (int i = 0; i < 16; ++i) c[i] = 0.f;
}

__device__ __forceinline__ void diag4(float c[16], float v, int dg) {
  if (dg) { c[0] += v; c[5] += v; c[10] += v; c[15] += v; }
}

// c = sc * (A + da*I) * (B + db*I).
// A col-form LDS (A[k*LN+i] = A[i][k]), B row-form (B[k*LN+j] = B[k][j]).
// Lane (bi,bj) owns C[4bi..][4bj..].  da/db/sc are compile-time after inline.
__device__ __forceinline__ void mm_gen(const float* A, const float* B, float c[16],
                                       int bi4, int bj4, float da, float db, float sc) {
  zero16(c);
#pragma unroll 4
  for (int k = 0; k < 32; ++k) {
    float4 a = *(const float4*)(A + k * LN + bi4);
    float4 b = *(const float4*)(B + k * LN + bj4);
    c[0] = fmaf(a.x, b.x, c[0]);  c[1] = fmaf(a.x, b.y, c[1]);
    c[2] = fmaf(a.x, b.z, c[2]);  c[3] = fmaf(a.x, b.w, c[3]);
    c[4] = fmaf(a.y, b.x, c[4]);  c[5] = fmaf(a.y, b.y, c[5]);
    c[6] = fmaf(a.y, b.z, c[6]);  c[7] = fmaf(a.y, b.w, c[7]);
    c[8] = fmaf(a.z, b.x, c[8]);  c[9] = fmaf(a.z, b.y, c[9]);
    c[10]= fmaf(a.z, b.z, c[10]); c[11]= fmaf(a.z, b.w, c[11]);
    c[12]= fmaf(a.w, b.x, c[12]); c[13]= fmaf(a.w, b.y, c[13]);
    c[14]= fmaf(a.w, b.z, c[14]); c[15]= fmaf(a.w, b.w, c[15]);
  }
  if (da != 0.f) {   // c += da * B[bi-rows][bj-cols]
#pragma unroll
    for (int di = 0; di < 4; ++di) {
      float4 b = *(const float4*)(B + (bi4 + di) * LN + bj4);
      c[di*4+0] = fmaf(da, b.x, c[di*4+0]);
      c[di*4+1] = fmaf(da, b.y, c[di*4+1]);
      c[di*4+2] = fmaf(da, b.z, c[di*4+2]);
      c[di*4+3] = fmaf(da, b.w, c[di*4+3]);
    }
  }
  if (db != 0.f) {   // c += db * A[bi-rows][bj-cols]  (A col-form)
#pragma unroll
    for (int dj = 0; dj < 4; ++dj) {
      float4 a = *(const float4*)(A + (bj4 + dj) * LN + bi4);
      c[0*4+dj] = fmaf(db, a.x, c[0*4+dj]);
      c[1*4+dj] = fmaf(db, a.y, c[1*4+dj]);
      c[2*4+dj] = fmaf(db, a.z, c[2*4+dj]);
      c[3*4+dj] = fmaf(db, a.w, c[3*4+dj]);
    }
    if (da != 0.f) diag4(c, da * db, bi4 == bj4);
  }
  if (sc != 1.f) {
#pragma unroll
    for (int i = 0; i < 16; ++i) c[i] *= sc;
  }
}

__device__ __forceinline__ void st_row(float* buf, const float c[16], int bi4, int bj4) {
#pragma unroll
  for (int di = 0; di < 4; ++di)
    *(float4*)(buf + (bi4 + di) * LN + bj4) =
        make_float4(c[di*4+0], c[di*4+1], c[di*4+2], c[di*4+3]);
}

__device__ __forceinline__ void st_col(float* buf, const float c[16], int bi4, int bj4) {
#pragma unroll
  for (int dj = 0; dj < 4; ++dj)
    *(float4*)(buf + (bj4 + dj) * LN + bi4) =
        make_float4(c[0*4+dj], c[1*4+dj], c[2*4+dj], c[3*4+dj]);
}

__device__ __forceinline__ void ldg_mat(const float* __restrict__ g, float c[16],
                                        int bi4, int bj4) {
#pragma unroll
  for (int di = 0; di < 4; ++di) {
    float4 v = *(const float4*)(g + (bi4 + di) * 32 + bj4);
    c[di*4+0] = v.x; c[di*4+1] = v.y; c[di*4+2] = v.z; c[di*4+3] = v.w;
  }
}
__device__ __forceinline__ void stg_mat(float* __restrict__ g, const float c[16],
                                        int bi4, int bj4, float s) {
#pragma unroll
  for (int di = 0; di < 4; ++di)
    *(float4*)(g + (bi4 + di) * 32 + bj4) =
        make_float4(c[di*4+0]*s, c[di*4+1]*s, c[di*4+2]*s, c[di*4+3]*s);
}

__device__ __forceinline__ void g2l(const float* __restrict__ g, float* buf, int lane) {
#pragma unroll
  for (int u = 0; u < 4; ++u) {
    int e = lane * 16 + u * 4;
    *(float4*)(buf + (e >> 5) * LN + (e & 31)) = *(const float4*)(g + e);
  }
}

// coupled Newton-Schulz sqrt/invsqrt (D=4 matrices only; 3 buffers OK there)
__device__ __forceinline__ void wave_sqrtinv(const float A[16], float Ysq[16], float Zis[16],
                                             float* YB, float* ZB, float* TB,
                                             int bi4, int bj4) {
  const int dg = (bi4 == bj4);
  float ss = 0.f;
#pragma unroll
  for (int i = 0; i < 16; ++i) ss += A[i] * A[i];
  const float th = sqrtf(wsum(ss));
  const float inv = 1.f / th;
  float Y[16], Z[16];
#pragma unroll
  for (int i = 0; i < 16; ++i) Y[i] = A[i] * inv;
  zero16(Z); diag4(Z, 1.f, dg);
  st_row(YB, Y, bi4, bj4);
  st_row(ZB, Z, bi4, bj4);
#pragma unroll 1
  for (int it = 0; it < 13; ++it) {
    float W[16], T[16];
    mm_gen(ZB, YB, W, bi4, bj4, 0.f, 0.f, 1.f);
#pragma unroll
    for (int i = 0; i < 16; ++i) T[i] = -0.5f * W[i];
    diag4(T, 1.5f, dg);
    st_row(TB, T, bi4, bj4);
    mm_gen(YB, TB, Y, bi4, bj4, 0.f, 0.f, 1.f);
    mm_gen(TB, ZB, Z, bi4, bj4, 0.f, 0.f, 1.f);
    st_row(YB, Y, bi4, bj4);
    st_row(ZB, Z, bi4, bj4);
  }
  const float sth = sqrtf(th), isth = 1.f / sth;
#pragma unroll
  for (int i = 0; i < 16; ++i) { Ysq[i] = Y[i] * sth; Zis[i] = Z[i] * isth; }
}

// L = log(P).  D1 holds P (row-form, symmetric).  Only 2 buffers used.
// Q=(P+I)^-1 via NS (iterate carried in regs: X <- 2X - M X^2), then
// S = I-2Q, S^2 = I-4Q+4Q^2, L = 2*S*g(S^2), g = 9-term Gregory.
__device__ __forceinline__ void wave_logm2(float* D1, float* D2, float L[16],
                                           int bi4, int bj4) {
  const int dg = (bi4 == bj4);
  float t[16], xs[16];
  mm_gen(D1, D1, t, bi4, bj4, 1.f, LOG_C0, -LOG_BE);   // t = -M*X0
  diag4(t, 2.f, dg);                                    // V1 = 2I - M X0
  st_row(D2, t, bi4, bj4);
  mm_gen(D1, D2, xs, bi4, bj4, LOG_C0, 0.f, LOG_BE);    // X1 = X0*V1
  st_row(D2, xs, bi4, bj4);
#pragma unroll 1
  for (int it = 0; it < 3; ++it) {
    mm_gen(D2, D2, t, bi4, bj4, 0.f, 0.f, 1.f);         // X^2
    st_row(D2, t, bi4, bj4);
    mm_gen(D1, D2, t, bi4, bj4, 1.f, 0.f, 1.f);         // M*X^2
#pragma unroll
    for (int i = 0; i < 16; ++i) xs[i] = 2.f * xs[i] - t[i];
    st_row(D2, xs, bi4, bj4);
  }
  mm_gen(D2, D2, t, bi4, bj4, 0.f, 0.f, 1.f);           // Q^2
  float s2[16];
#pragma unroll
  for (int i = 0; i < 16; ++i) s2[i] = 4.f * t[i] - 4.f * xs[i];
  diag4(s2, 1.f, dg);
  st_row(D1, s2, bi4, bj4);                             // D1 = S^2
#pragma unroll
  for (int i = 0; i < 16; ++i) xs[i] = -2.f * xs[i];
  diag4(xs, 1.f, dg);                                   // xs = S
  float h[16];
#pragma unroll
  for (int i = 0; i < 16; ++i) h[i] = (1.f / 17.f) * s2[i];
  diag4(h, 1.f / 15.f, dg);
  st_row(D2, h, bi4, bj4);
#pragma unroll 1
  for (int j = 6; j >= 0; --j) {
    mm_gen(D1, D2, h, bi4, bj4, 0.f, 0.f, 1.f);
    diag4(h, 1.f / (float)(2 * j + 1), dg);
    st_row(D2, h, bi4, bj4);
  }
  st_row(D1, xs, bi4, bj4);                             // D1 = S
  mm_gen(D1, D2, L, bi4, bj4, 0.f, 0.f, 2.f);           // L = 2*S*g(S^2)
}

// ------------------------------- kernels -----------------------------------

__global__ __launch_bounds__(64) void k1_g0sum(const float* __restrict__ X,
                                               const int* __restrict__ ds,
                                               float* __restrict__ ws, int q) {
  const int n = blockIdx.x, lane = threadIdx.x;
  const int d = ds[n];
  float acc[16];
  zero16(acc);
  const float* base = X + (size_t)n * q * 1024 + lane * 16;
#pragma unroll 4
  for (int j = 0; j < 16; ++j) {
    const float* g = base + (size_t)j * 1024;
#pragma unroll
    for (int u = 0; u < 4; ++u) {
      float4 v = *(const float4*)(g + u * 4);
      acc[u*4+0] += v.x; acc[u*4+1] += v.y; acc[u*4+2] += v.z; acc[u*4+3] += v.w;
    }
  }
  float* dst = ws + WS_G0SUM + d * 1024 + lane * 16;
#pragma unroll
  for (int i = 0; i < 16; ++i) atomicAdd(dst + i, acc[i]);
}

__global__ __launch_bounds__(128) void k2_g0funcs(float* __restrict__ ws,
                                                  const int* __restrict__ ds,
                                                  const float* __restrict__ B,
                                                  int N, int q) {
  __shared__ float D[2][3][MSZ];
  const int d = blockIdx.x, tid = threadIdx.x;
  const int w = tid >> 6, lane = tid & 63;
  const int bi4 = (lane >> 3) * 4, bj4 = (lane & 7) * 4;
  float A[16], Y[16], Z[16];
  if (w == 0) {
    int cnt = 0;
    for (int i = lane; i < N; i += 64) cnt += (ds[i] == d) ? 1 : 0;
    const float cntf = wsum((float)cnt);
    if (lane == 0) ws[WS_CNT + d] = cntf;
    ldg_mat(ws + WS_G0SUM + d * 1024, A, bi4, bj4);
    const float s = 1.f / ((float)q * cntf);
#pragma unroll
    for (int i = 0; i < 16; ++i) A[i] *= s;
    wave_sqrtinv(A, Y, Z, D[0][0], D[0][1], D[0][2], bi4, bj4);
    stg_mat(ws + WS_G0SQ  + d * 1024, Y, bi4, bj4, 1.f);
    stg_mat(ws + WS_G0ISQ + d * 1024, Z, bi4, bj4, 1.f);
  } else {
    ldg_mat(B + d * 1024, A, bi4, bj4);
    wave_sqrtinv(A, Y, Z, D[1][0], D[1][1], D[1][2], bi4, bj4);
    stg_mat(ws + WS_BSQ + d * 1024, Y, bi4, bj4, 1.f);
  }
}

__global__ __launch_bounds__(128) void k3_gt(const float* __restrict__ X,
                                             const int* __restrict__ ds,
                                             float* __restrict__ ws, int q) {
  __shared__ float GiB[MSZ], GsB[MSZ], DYN[2][2][MSZ];
  const int n = blockIdx.x, tid = threadIdx.x;
  const int w = tid >> 6, lane = tid & 63;
  const int bi4 = (lane >> 3) * 4, bj4 = (lane & 7) * 4;
  const int d = ds[n];
  if (w == 0) g2l(ws + WS_G0ISQ + d * 1024, GiB, lane);
  else        g2l(ws + WS_G0SQ  + d * 1024, GsB, lane);
  __syncthreads();
  float* D1 = DYN[w][0]; float* D2 = DYN[w][1];
  float acc[16];
  zero16(acc);
  const int half = q >> 1;
#pragma unroll 1
  for (int j = 0; j < half; ++j) {
    const size_t m = (size_t)n * q + (size_t)w * half + j;
    g2l(X + m * 1024, D1, lane);
    float t[16], L[16];
    mm_gen(GiB, D1, t, bi4, bj4, 0.f, 0.f, 1.f);  st_col(D2, t, bi4, bj4);
    mm_gen(D2, GiB, t, bi4, bj4, 0.f, 0.f, 1.f);  st_row(D1, t, bi4, bj4);
    wave_logm2(D1, D2, L, bi4, bj4);
    st_row(D1, L, bi4, bj4);
    mm_gen(GsB, D1, t, bi4, bj4, 0.f, 0.f, 1.f);  st_col(D2, t, bi4, bj4);
    mm_gen(D2, GsB, t, bi4, bj4, 0.f, 0.f, 1.f);
#pragma unroll
    for (int i = 0; i < 16; ++i) acc[i] += t[i];
  }
  float* dst = ws + WS_GTSUM + d * 1024;
#pragma unroll
  for (int di = 0; di < 4; ++di)
#pragma unroll
    for (int dj = 0; dj < 4; ++dj)
      atomicAdd(dst + (bi4 + di) * 32 + bj4 + dj, acc[di * 4 + dj]);
}

__global__ __launch_bounds__(64) void k4_mean(float* __restrict__ ws, int q) {
  __shared__ float GB[MSZ], D1[MSZ], D2[MSZ], D3[MSZ];
  const int d = blockIdx.x, lane = threadIdx.x;
  const int bi4 = (lane >> 3) * 4, bj4 = (lane & 7) * 4;
  const int dg = (bi4 == bj4);
  const float cntf = ws[WS_CNT + d];
  float c[16], t[16];
  ldg_mat(ws + WS_G0ISQ + d * 1024, c, bi4, bj4); st_row(GB, c, bi4, bj4);
  ldg_mat(ws + WS_GTSUM + d * 1024, c, bi4, bj4);
  const float s = 1.f / ((float)q * cntf);
#pragma unroll
  for (int i = 0; i < 16; ++i) c[i] *= s;
  st_row(D1, c, bi4, bj4);
  mm_gen(GB, D1, t, bi4, bj4, 0.f, 0.f, 1.f); st_col(D2, t, bi4, bj4);
  mm_gen(D2, GB, t, bi4, bj4, 0.f, 0.f, 1.f); st_row(D1, t, bi4, bj4);  // E
  float H[16];
  zero16(H); diag4(H, 2.7557319e-7f, dg);                               // 1/10!
  st_row(D2, H, bi4, bj4);
  float ck = 2.7557319e-7f;
#pragma unroll 1
  for (int kk = 9; kk >= 0; --kk) {
    ck *= (float)(kk + 1);
    mm_gen(D1, D2, H, bi4, bj4, 0.f, 0.f, 1.f);
    diag4(H, ck, dg);
    st_row(D2, H, bi4, bj4);
  }                                                                     // exp(E)
  ldg_mat(ws + WS_G0SQ + d * 1024, c, bi4, bj4); st_row(GB, c, bi4, bj4);
  st_row(D1, H, bi4, bj4);
  mm_gen(GB, D1, t, bi4, bj4, 0.f, 0.f, 1.f); st_col(D2, t, bi4, bj4);
  mm_gen(D2, GB, t, bi4, bj4, 0.f, 0.f, 1.f);                           // G
  float Y[16], Z[16];
  wave_sqrtinv(t, Y, Z, D1, D2, D3, bi4, bj4);
  stg_mat(ws + WS_GISQ + d * 1024, Z, bi4, bj4, 1.f);
}

__global__ __launch_bounds__(128) void k5_logxc(const float* __restrict__ X,
                                                const int* __restrict__ ds,
                                                float* __restrict__ ws,
                                                float* __restrict__ Lout, int q) {
  __shared__ float GiB[MSZ], DYN[2][2][MSZ];
  const int n = blockIdx.x, tid = threadIdx.x;
  const int w = tid >> 6, lane = tid & 63;
  const int bi4 = (lane >> 3) * 4, bj4 = (lane & 7) * 4;
  const int d = ds[n];
  if (w == 0) g2l(ws + WS_GISQ + d * 1024, GiB, lane);
  __syncthreads();
  float* D1 = DYN[w][0]; float* D2 = DYN[w][1];
  float vacc = 0.f;
  const int half = q >> 1;
#pragma unroll 1
  for (int j = 0; j < half; ++j) {
    const size_t m = (size_t)n * q + (size_t)w * half + j;
    g2l(X + m * 1024, D1, lane);
    float t[16], L[16];
    mm_gen(GiB, D1, t, bi4, bj4, 0.f, 0.f, 1.f);  st_col(D2, t, bi4, bj4);
    mm_gen(D2, GiB, t, bi4, bj4, 0.f, 0.f, 1.f);  st_row(D1, t, bi4, bj4);  // Xc
    wave_logm2(D1, D2, L, bi4, bj4);
    float sq = 0.f;
#pragma unroll
    for (int i = 0; i < 16; ++i) sq += L[i] * L[i];
    vacc += sq;
    stg_mat(Lout + m * 1024, L, bi4, bj4, 1.f);
  }
  vacc = wsum(vacc);
  if (lane == 0) atomicAdd(ws + WS_VAR + d, vacc);
}

__global__ __launch_bounds__(64) void k6_p(float* __restrict__ ws, int q, int D) {
  const int lane = threadIdx.x;
  if (lane < D) {
    const float cntf = ws[WS_CNT + lane];
    const float var = ws[WS_VAR + lane] / ((float)q * cntf);
    ws[WS_P + lane] = sqrtf(1.f / (var + 1e-5f));
  }
}

__global__ __launch_bounds__(128) void k7_out(const int* __restrict__ ds,
                                              const float* __restrict__ ws,
                                              const float* __restrict__ R,
                                              float* __restrict__ io, int q) {
  __shared__ float RcB[MSZ], BsB[MSZ], DYN[2][2][MSZ];
  const int n = blockIdx.x, tid = threadIdx.x;
  const int w = tid >> 6, lane = tid & 63;
  const int bi4 = (lane >> 3) * 4, bj4 = (lane & 7) * 4;
  const int dg = (bi4 == bj4);
  const int d = ds[n];
  if (w == 0) { float c[16]; ldg_mat(R + d * 1024, c, bi4, bj4);           st_col(RcB, c, bi4, bj4); }
  else        { float c[16]; ldg_mat(ws + WS_BSQ + d * 1024, c, bi4, bj4); st_row(BsB, c, bi4, bj4); }
  __syncthreads();
  const float ph = 0.5f * ws[WS_P + d];
  float* D1 = DYN[w][0]; float* D2 = DYN[w][1];
  const int half = q >> 1;
#pragma unroll 1
  for (int j = 0; j < half; ++j) {
    const size_t m = (size_t)n * q + (size_t)w * half + j;
    float c[16], h[16], t[16];
    ldg_mat(io + m * 1024, c, bi4, bj4);
#pragma unroll
    for (int i = 0; i < 16; ++i) c[i] *= ph;          // Sh = (p/2)*L
    st_row(D1, c, bi4, bj4);
    // exp(Sh), Taylor deg 10, Horner
#pragma unroll
    for (int i = 0; i < 16; ++i) h[i] = 2.7557319e-7f * c[i];     // 1/10!
    diag4(h, 2.7557319e-6f, dg);                                   // 1/9!
    st_row(D2, h, bi4, bj4);
    float ck = 2.7557319e-6f;
#pragma unroll 1
    for (int kk = 8; kk >= 0; --kk) {
      ck *= (float)(kk + 1);
      mm_gen(D1, D2, h, bi4, bj4, 0.f, 0.f, 1.f);
      diag4(h, ck, dg);
      st_row(D2, h, bi4, bj4);
    }
    mm_gen(D2, D2, t, bi4, bj4, 0.f, 0.f, 1.f);  st_row(D1, t, bi4, bj4);  // Xp = H^2
    mm_gen(RcB, D1, t, bi4, bj4, 0.f, 0.f, 1.f); st_col(D2, t, bi4, bj4);  // R*Xp
    mm_gen(D2, RcB, t, bi4, bj4, 0.f, 0.f, 1.f); st_row(D1, t, bi4, bj4);  // *R^T
    mm_gen(BsB, D1, t, bi4, bj4, 0.f, 0.f, 1.f); st_col(D2, t, bi4, bj4);  // Bs*Xr
    mm_gen(D2, BsB, t, bi4, bj4, 0.f, 0.f, 1.f);                           // *Bs
    stg_mat(io + m * 1024, t, bi4, bj4, 1.f);
  }
}

// ------------------------------- launcher ----------------------------------

extern "C" void kernel_launch(void* const* d_in, const int* in_sizes, int n_in,
                              void* d_out, int out_size, void* d_ws, size_t ws_size,
                              hipStream_t stream) {
  const float* X  = (const float*)d_in[0];
  const int*   ds = (const int*)d_in[1];
  const float* R  = (const float*)d_in[2];
  const float* B  = (const float*)d_in[3];
  float* out = (float*)d_out;
  float* ws  = (float*)d_ws;
  const int N = in_sizes[1];
  const int q = in_sizes[0] / (N * 1024);
  const int D = in_sizes[2] / 1024;
  (void)n_in; (void)out_size; (void)ws_size;

  hipMemsetAsync(d_ws, 0, WS_ZERO * sizeof(float), stream);
  k1_g0sum  <<<dim3(N), dim3(64),  0, stream>>>(X, ds, ws, q);
  k2_g0funcs<<<dim3(D), dim3(128), 0, stream>>>(ws, ds, B, N, q);
  k3_gt     <<<dim3(N), dim3(128), 0, stream>>>(X, ds, ws, q);
  k4_mean   <<<dim3(D), dim3(64),  0, stream>>>(ws, q);
  k5_logxc  <<<dim3(N), dim3(128), 0, stream>>>(X, ds, ws, out, q);
  k6_p      <<<dim3(1), dim3(64),  0, stream>>>(ws, q, D);
  k7_out    <<<dim3(N), dim3(128), 0, stream>>>(ds, ws, R, out, q);
}

// Round 3
// 1111.226 us; speedup vs baseline: 2.6596x; 2.2699x over previous
//
#include <hip/hip_runtime.h>

// ---------------------------------------------------------------------------
// DomainGeneralisationBN (SPD batchnorm) — R3: MFMA split-bf16 matmuls.
// All 32x32 matmuls in k3/k5/k7 via v_mfma_f32_32x32x16_bf16 with hi/lo
// split-bf16 operands (C = AhBh + AhBl + AlBh, fp32 accumulate).
// Storage: transposed packed layout s[n][k-pair dwords], 36-dword row stride
// (16 hi pairs, 16 lo pairs, 4 pad).  All products ordered right-to-left so
// intermediates are only consumed as B-operands (contiguous frag reads).
// C-layout (verified): col=lane&31, row=(reg&3)+8*(reg>>2)+4*(lane>>5).
// A/B frag: m(or n)=lane&31, k=(lane>>5)*8+j.
// k2/k4 (D=4 matrices) remain fp32-VALU.  L stashed fp32 in d_out (k5->k7).
// ---------------------------------------------------------------------------

#define LN  36
#define MSZ (32 * LN)

#define SROW  36
#define SMATU (32 * SROW)   // dwords per split-bf16 matrix buffer

// workspace layout (float offsets)
#define WS_G0SUM 0
#define WS_GTSUM 4096
#define WS_VAR   8192
#define WS_CNT   8196
#define WS_P     8200
#define WS_G0SQ  8208
#define WS_G0ISQ 12304
#define WS_GISQ  16400
#define WS_BSQ   20496
#define WS_ZERO  8208

// (P+I)^-1 NS init: X0 = AL*I + BE*M, Chebyshev on eigs(M) in [1.15, 8]
#define LOG_AL 0.6073551f
#define LOG_BE (-0.0663776f)

typedef __attribute__((ext_vector_type(8)))  short bf16x8;
typedef __attribute__((ext_vector_type(16))) float f32x16;

union FragU { uint4 u; bf16x8 v; };

__device__ __forceinline__ float wsum(float v) {
#pragma unroll
  for (int o = 32; o > 0; o >>= 1) v += __shfl_xor(v, o, 64);
  return v;
}

// ---------------- MFMA-path helpers ----------------

__device__ __forceinline__ f32x16 mm_mfma(const unsigned* A, const unsigned* B, int ro) {
  f32x16 c;
#pragma unroll
  for (int i = 0; i < 16; ++i) c[i] = 0.f;
#pragma unroll
  for (int t = 0; t < 2; ++t) {
    FragU ah, al, bh, bl;
    ah.u = *(const uint4*)(A + ro + t * 8);
    al.u = *(const uint4*)(A + ro + 16 + t * 8);
    bh.u = *(const uint4*)(B + ro + t * 8);
    bl.u = *(const uint4*)(B + ro + 16 + t * 8);
    c = __builtin_amdgcn_mfma_f32_32x32x16_bf16(ah.v, bh.v, c, 0, 0, 0);
    c = __builtin_amdgcn_mfma_f32_32x32x16_bf16(ah.v, bl.v, c, 0, 0, 0);
    c = __builtin_amdgcn_mfma_f32_32x32x16_bf16(al.v, bh.v, c, 0, 0, 0);
  }
  return c;
}

// store C-regs into split-bf16 transposed storage (result usable as B-operand;
// as A-operand too when symmetric)
__device__ __forceinline__ void st_split(unsigned* buf, const f32x16 c,
                                         int ccol, int h) {
  const int wo = ccol * SROW + 2 * h;
#pragma unroll
  for (int g = 0; g < 4; ++g) {
    const float x0 = c[4*g+0], x1 = c[4*g+1], x2 = c[4*g+2], x3 = c[4*g+3];
    const unsigned a0 = __float_as_uint(x0) + 0x8000u;
    const unsigned a1 = __float_as_uint(x1) + 0x8000u;
    const unsigned a2 = __float_as_uint(x2) + 0x8000u;
    const unsigned a3 = __float_as_uint(x3) + 0x8000u;
    const float l0 = x0 - __uint_as_float(a0 & 0xFFFF0000u);
    const float l1 = x1 - __uint_as_float(a1 & 0xFFFF0000u);
    const float l2 = x2 - __uint_as_float(a2 & 0xFFFF0000u);
    const float l3 = x3 - __uint_as_float(a3 & 0xFFFF0000u);
    uint2 hp, lp;
    hp.x = __builtin_amdgcn_perm(a1, a0, 0x07060302u);
    hp.y = __builtin_amdgcn_perm(a3, a2, 0x07060302u);
    lp.x = __builtin_amdgcn_perm(__float_as_uint(l1), __float_as_uint(l0), 0x07060302u);
    lp.y = __builtin_amdgcn_perm(__float_as_uint(l3), __float_as_uint(l2), 0x07060302u);
    *(uint2*)(buf + wo + 4*g)      = hp;
    *(uint2*)(buf + wo + 16 + 4*g) = lp;
  }
}

// global fp32 row-major 32x32 -> split-bf16 LDS storage (row-major phys).
// Symmetric matrices: serves as A and B.  Non-symmetric M (e.g. R): serves as
// A-operand of M and B-operand of M^T — exactly the uses we need.
__device__ __forceinline__ void x2l(const float* __restrict__ g, unsigned* buf,
                                    int lane) {
  const int n = lane >> 1, cb = (lane & 1) * 8;
  unsigned hi[8], lo[8];
#pragma unroll
  for (int u = 0; u < 4; ++u) {
    float4 v = *(const float4*)(g + lane * 16 + u * 4);
    const unsigned a0 = __float_as_uint(v.x) + 0x8000u;
    const unsigned a1 = __float_as_uint(v.y) + 0x8000u;
    const unsigned a2 = __float_as_uint(v.z) + 0x8000u;
    const unsigned a3 = __float_as_uint(v.w) + 0x8000u;
    const float l0 = v.x - __uint_as_float(a0 & 0xFFFF0000u);
    const float l1 = v.y - __uint_as_float(a1 & 0xFFFF0000u);
    const float l2 = v.z - __uint_as_float(a2 & 0xFFFF0000u);
    const float l3 = v.w - __uint_as_float(a3 & 0xFFFF0000u);
    hi[2*u]   = __builtin_amdgcn_perm(a1, a0, 0x07060302u);
    hi[2*u+1] = __builtin_amdgcn_perm(a3, a2, 0x07060302u);
    lo[2*u]   = __builtin_amdgcn_perm(__float_as_uint(l1), __float_as_uint(l0), 0x07060302u);
    lo[2*u+1] = __builtin_amdgcn_perm(__float_as_uint(l3), __float_as_uint(l2), 0x07060302u);
  }
  *(uint4*)(buf + n * SROW + cb)          = make_uint4(hi[0], hi[1], hi[2], hi[3]);
  *(uint4*)(buf + n * SROW + cb + 4)      = make_uint4(hi[4], hi[5], hi[6], hi[7]);
  *(uint4*)(buf + n * SROW + 16 + cb)     = make_uint4(lo[0], lo[1], lo[2], lo[3]);
  *(uint4*)(buf + n * SROW + 16 + cb + 4) = make_uint4(lo[4], lo[5], lo[6], lo[7]);
}

__device__ __forceinline__ void addID(f32x16& c, float v, const float* dm) {
#pragma unroll
  for (int i = 0; i < 16; ++i) c[i] = fmaf(v, dm[i], c[i]);
}

// L = log(P), P = C-regs of the congruence product (SPD, eigs in ~[0.2,5.5]).
// Uses D1, D2.  On exit D1=S, D2=H (both dead to caller).
__device__ __forceinline__ f32x16 logm_mfma(unsigned* D1, unsigned* D2,
                                            f32x16 M, int ro, int ccol, int h,
                                            const float* dm) {
  addID(M, 1.f, dm);                         // M = P + I
  st_split(D1, M, ccol, h);
  f32x16 t = mm_mfma(D1, D1, ro);            // M^2
  f32x16 V;
#pragma unroll
  for (int i = 0; i < 16; ++i) V[i] = -(LOG_AL * M[i] + LOG_BE * t[i]);
  addID(V, 2.f, dm);                         // V = 2I - M*X0
  st_split(D2, V, ccol, h);
  t = mm_mfma(D1, D2, ro);                   // M*V
  f32x16 X;
#pragma unroll
  for (int i = 0; i < 16; ++i) X[i] = LOG_AL * V[i] + LOG_BE * t[i];  // X1=X0*V
  st_split(D2, X, ccol, h);
#pragma unroll 1
  for (int it = 0; it < 3; ++it) {           // X <- 2X - M X^2
    t = mm_mfma(D2, D2, ro);
    st_split(D2, t, ccol, h);
    t = mm_mfma(D1, D2, ro);
#pragma unroll
    for (int i = 0; i < 16; ++i) X[i] = 2.f * X[i] - t[i];
    st_split(D2, X, ccol, h);
  }
  // Q = X ~= M^-1.  S = I-2Q, S^2 = I-4Q+4Q^2
  t = mm_mfma(D2, D2, ro);                   // Q^2
  f32x16 S2;
#pragma unroll
  for (int i = 0; i < 16; ++i) S2[i] = 4.f * (t[i] - X[i]);
  addID(S2, 1.f, dm);
  st_split(D1, S2, ccol, h);
  f32x16 S;
#pragma unroll
  for (int i = 0; i < 16; ++i) S[i] = -2.f * X[i];
  addID(S, 1.f, dm);
  // Gregory: g(y)=sum_{j=0..8} y^j/(2j+1), Horner
  f32x16 H;
#pragma unroll
  for (int i = 0; i < 16; ++i) H[i] = (1.f / 17.f) * S2[i];
  addID(H, 1.f / 15.f, dm);
  st_split(D2, H, ccol, h);
#pragma unroll 1
  for (int j = 6; j >= 0; --j) {
    H = mm_mfma(D1, D2, ro);
    addID(H, 1.f / (float)(2 * j + 1), dm);
    st_split(D2, H, ccol, h);
  }
  st_split(D1, S, ccol, h);
  t = mm_mfma(D1, D2, ro);                   // S * g(S^2)
#pragma unroll
  for (int i = 0; i < 16; ++i) t[i] *= 2.f;
  return t;
}

// ---------------- fp32-VALU helpers (k2/k4 only, D=4 matrices) ----------------

__device__ __forceinline__ void zero16(float c[16]) {
#pragma unroll
  for (int i = 0; i < 16; ++i) c[i] = 0.f;
}
__device__ __forceinline__ void diag4(float c[16], float v, int dg) {
  if (dg) { c[0] += v; c[5] += v; c[10] += v; c[15] += v; }
}
__device__ __forceinline__ void mm_gen(const float* A, const float* B, float c[16],
                                       int bi4, int bj4) {
  zero16(c);
#pragma unroll 4
  for (int k = 0; k < 32; ++k) {
    float4 a = *(const float4*)(A + k * LN + bi4);
    float4 b = *(const float4*)(B + k * LN + bj4);
    c[0] = fmaf(a.x, b.x, c[0]);  c[1] = fmaf(a.x, b.y, c[1]);
    c[2] = fmaf(a.x, b.z, c[2]);  c[3] = fmaf(a.x, b.w, c[3]);
    c[4] = fmaf(a.y, b.x, c[4]);  c[5] = fmaf(a.y, b.y, c[5]);
    c[6] = fmaf(a.y, b.z, c[6]);  c[7] = fmaf(a.y, b.w, c[7]);
    c[8] = fmaf(a.z, b.x, c[8]);  c[9] = fmaf(a.z, b.y, c[9]);
    c[10]= fmaf(a.z, b.z, c[10]); c[11]= fmaf(a.z, b.w, c[11]);
    c[12]= fmaf(a.w, b.x, c[12]); c[13]= fmaf(a.w, b.y, c[13]);
    c[14]= fmaf(a.w, b.z, c[14]); c[15]= fmaf(a.w, b.w, c[15]);
  }
}
__device__ __forceinline__ void st_row(float* buf, const float c[16], int bi4, int bj4) {
#pragma unroll
  for (int di = 0; di < 4; ++di)
    *(float4*)(buf + (bi4 + di) * LN + bj4) =
        make_float4(c[di*4+0], c[di*4+1], c[di*4+2], c[di*4+3]);
}
__device__ __forceinline__ void st_colf(float* buf, const float c[16], int bi4, int bj4) {
#pragma unroll
  for (int dj = 0; dj < 4; ++dj)
    *(float4*)(buf + (bj4 + dj) * LN + bi4) =
        make_float4(c[0*4+dj], c[1*4+dj], c[2*4+dj], c[3*4+dj]);
}
__device__ __forceinline__ void ldg_mat(const float* __restrict__ g, float c[16],
                                        int bi4, int bj4) {
#pragma unroll
  for (int di = 0; di < 4; ++di) {
    float4 v = *(const float4*)(g + (bi4 + di) * 32 + bj4);
    c[di*4+0] = v.x; c[di*4+1] = v.y; c[di*4+2] = v.z; c[di*4+3] = v.w;
  }
}
__device__ __forceinline__ void stg_mat(float* __restrict__ g, const float c[16],
                                        int bi4, int bj4) {
#pragma unroll
  for (int di = 0; di < 4; ++di)
    *(float4*)(g + (bi4 + di) * 32 + bj4) =
        make_float4(c[di*4+0], c[di*4+1], c[di*4+2], c[di*4+3]);
}
__device__ __forceinline__ void wave_sqrtinv(const float A[16], float Ysq[16], float Zis[16],
                                             float* YB, float* ZB, float* TB,
                                             int bi4, int bj4) {
  const int dg = (bi4 == bj4);
  float ss = 0.f;
#pragma unroll
  for (int i = 0; i < 16; ++i) ss += A[i] * A[i];
  const float th = sqrtf(wsum(ss));
  const float inv = 1.f / th;
  float Y[16], Z[16];
#pragma unroll
  for (int i = 0; i < 16; ++i) Y[i] = A[i] * inv;
  zero16(Z); diag4(Z, 1.f, dg);
  st_row(YB, Y, bi4, bj4);
  st_row(ZB, Z, bi4, bj4);
#pragma unroll 1
  for (int it = 0; it < 13; ++it) {
    float W[16], T[16];
    mm_gen(ZB, YB, W, bi4, bj4);
#pragma unroll
    for (int i = 0; i < 16; ++i) T[i] = -0.5f * W[i];
    diag4(T, 1.5f, dg);
    st_row(TB, T, bi4, bj4);
    mm_gen(YB, TB, Y, bi4, bj4);
    mm_gen(TB, ZB, Z, bi4, bj4);
    st_row(YB, Y, bi4, bj4);
    st_row(ZB, Z, bi4, bj4);
  }
  const float sth = sqrtf(th), isth = 1.f / sth;
#pragma unroll
  for (int i = 0; i < 16; ++i) { Ysq[i] = Y[i] * sth; Zis[i] = Z[i] * isth; }
}

// ------------------------------- kernels -----------------------------------

__global__ __launch_bounds__(64) void k1_g0sum(const float* __restrict__ X,
                                               const int* __restrict__ ds,
                                               float* __restrict__ ws, int q) {
  const int n = blockIdx.x, lane = threadIdx.x;
  const int d = ds[n];
  float acc[16];
  zero16(acc);
  const float* base = X + (size_t)n * q * 1024 + lane * 16;
#pragma unroll 4
  for (int j = 0; j < 16; ++j) {
    const float* g = base + (size_t)j * 1024;
#pragma unroll
    for (int u = 0; u < 4; ++u) {
      float4 v = *(const float4*)(g + u * 4);
      acc[u*4+0] += v.x; acc[u*4+1] += v.y; acc[u*4+2] += v.z; acc[u*4+3] += v.w;
    }
  }
  float* dst = ws + WS_G0SUM + d * 1024 + lane * 16;
#pragma unroll
  for (int i = 0; i < 16; ++i) atomicAdd(dst + i, acc[i]);
}

__global__ __launch_bounds__(128) void k2_g0funcs(float* __restrict__ ws,
                                                  const int* __restrict__ ds,
                                                  const float* __restrict__ B,
                                                  int N, int q) {
  __shared__ float D[2][3][MSZ];
  const int d = blockIdx.x, tid = threadIdx.x;
  const int w = tid >> 6, lane = tid & 63;
  const int bi4 = (lane >> 3) * 4, bj4 = (lane & 7) * 4;
  float A[16], Y[16], Z[16];
  if (w == 0) {
    int cnt = 0;
    for (int i = lane; i < N; i += 64) cnt += (ds[i] == d) ? 1 : 0;
    const float cntf = wsum((float)cnt);
    if (lane == 0) ws[WS_CNT + d] = cntf;
    ldg_mat(ws + WS_G0SUM + d * 1024, A, bi4, bj4);
    const float s = 1.f / ((float)q * cntf);
#pragma unroll
    for (int i = 0; i < 16; ++i) A[i] *= s;
    wave_sqrtinv(A, Y, Z, D[0][0], D[0][1], D[0][2], bi4, bj4);
    stg_mat(ws + WS_G0SQ  + d * 1024, Y, bi4, bj4);
    stg_mat(ws + WS_G0ISQ + d * 1024, Z, bi4, bj4);
  } else {
    ldg_mat(B + d * 1024, A, bi4, bj4);
    wave_sqrtinv(A, Y, Z, D[1][0], D[1][1], D[1][2], bi4, bj4);
    stg_mat(ws + WS_BSQ + d * 1024, Y, bi4, bj4);
  }
}

__global__ __launch_bounds__(128) void k3_gt(const float* __restrict__ X,
                                             const int* __restrict__ ds,
                                             float* __restrict__ ws, int q) {
  __shared__ unsigned GiB[SMATU], GsB[SMATU];
  __shared__ unsigned DYN[2][2][SMATU];
  const int n = blockIdx.x, tid = threadIdx.x;
  const int w = tid >> 6, lane = tid & 63;
  const int ccol = lane & 31, h = lane >> 5;
  const int ro = ccol * SROW + h * 4;
  float dm[16];
#pragma unroll
  for (int i = 0; i < 16; ++i) {
    const int row = (i & 3) + 8 * (i >> 2) + 4 * h;
    dm[i] = (row == ccol) ? 1.f : 0.f;
  }
  const int d = ds[n];
  if (w == 0) x2l(ws + WS_G0ISQ + d * 1024, GiB, lane);
  else        x2l(ws + WS_G0SQ  + d * 1024, GsB, lane);
  __syncthreads();
  unsigned* D1 = DYN[w][0]; unsigned* D2 = DYN[w][1];
  f32x16 acc;
#pragma unroll
  for (int i = 0; i < 16; ++i) acc[i] = 0.f;
  const int half = q >> 1;
#pragma unroll 1
  for (int j = 0; j < half; ++j) {
    const size_t m = (size_t)n * q + (size_t)w * half + j;
    x2l(X + m * 1024, D1, lane);
    f32x16 u = mm_mfma(D1, GiB, ro);           // X * Gi
    st_split(D2, u, ccol, h);
    f32x16 P = mm_mfma(GiB, D2, ro);           // Gi X Gi
    f32x16 L = logm_mfma(D1, D2, P, ro, ccol, h, dm);
    st_split(D1, L, ccol, h);
    u = mm_mfma(D1, GsB, ro);                  // L * Gs
    st_split(D2, u, ccol, h);
    u = mm_mfma(GsB, D2, ro);                  // Gs L Gs
#pragma unroll
    for (int i = 0; i < 16; ++i) acc[i] += u[i];
  }
  float* dst = ws + WS_GTSUM + d * 1024;
#pragma unroll
  for (int i = 0; i < 16; ++i) {
    const int row = (i & 3) + 8 * (i >> 2) + 4 * h;
    atomicAdd(dst + row * 32 + ccol, acc[i]);
  }
}

__global__ __launch_bounds__(64) void k4_mean(float* __restrict__ ws, int q) {
  __shared__ float GB[MSZ], D1[MSZ], D2[MSZ], D3[MSZ];
  const int d = blockIdx.x, lane = threadIdx.x;
  const int bi4 = (lane >> 3) * 4, bj4 = (lane & 7) * 4;
  const int dg = (bi4 == bj4);
  const float cntf = ws[WS_CNT + d];
  float c[16], t[16];
  ldg_mat(ws + WS_G0ISQ + d * 1024, c, bi4, bj4); st_row(GB, c, bi4, bj4);
  ldg_mat(ws + WS_GTSUM + d * 1024, c, bi4, bj4);
  const float s = 1.f / ((float)q * cntf);
#pragma unroll
  for (int i = 0; i < 16; ++i) c[i] *= s;
  st_row(D1, c, bi4, bj4);
  mm_gen(GB, D1, t, bi4, bj4); st_colf(D2, t, bi4, bj4);
  mm_gen(D2, GB, t, bi4, bj4); st_row(D1, t, bi4, bj4);   // E = Gi GT Gi
  float H[16];
  zero16(H); diag4(H, 2.7557319e-7f, dg);                 // 1/10!
  st_row(D2, H, bi4, bj4);
  float ck = 2.7557319e-7f;
#pragma unroll 1
  for (int kk = 9; kk >= 0; --kk) {
    ck *= (float)(kk + 1);
    mm_gen(D1, D2, H, bi4, bj4);
    diag4(H, ck, dg);
    st_row(D2, H, bi4, bj4);
  }                                                       // exp(E)
  ldg_mat(ws + WS_G0SQ + d * 1024, c, bi4, bj4); st_row(GB, c, bi4, bj4);
  st_row(D1, H, bi4, bj4);
  mm_gen(GB, D1, t, bi4, bj4); st_colf(D2, t, bi4, bj4);
  mm_gen(D2, GB, t, bi4, bj4);                            // G
  float Y[16], Z[16];
  wave_sqrtinv(t, Y, Z, D1, D2, D3, bi4, bj4);
  stg_mat(ws + WS_GISQ + d * 1024, Z, bi4, bj4);
}

__global__ __launch_bounds__(128) void k5_logxc(const float* __restrict__ X,
                                                const int* __restrict__ ds,
                                                float* __restrict__ ws,
                                                float* __restrict__ Lout, int q) {
  __shared__ unsigned GiB[SMATU];
  __shared__ unsigned DYN[2][2][SMATU];
  const int n = blockIdx.x, tid = threadIdx.x;
  const int w = tid >> 6, lane = tid & 63;
  const int ccol = lane & 31, h = lane >> 5;
  const int ro = ccol * SROW + h * 4;
  float dm[16];
#pragma unroll
  for (int i = 0; i < 16; ++i) {
    const int row = (i & 3) + 8 * (i >> 2) + 4 * h;
    dm[i] = (row == ccol) ? 1.f : 0.f;
  }
  const int d = ds[n];
  if (w == 0) x2l(ws + WS_GISQ + d * 1024, GiB, lane);
  __syncthreads();
  unsigned* D1 = DYN[w][0]; unsigned* D2 = DYN[w][1];
  float vacc = 0.f;
  const int half = q >> 1;
#pragma unroll 1
  for (int j = 0; j < half; ++j) {
    const size_t m = (size_t)n * q + (size_t)w * half + j;
    x2l(X + m * 1024, D1, lane);
    f32x16 u = mm_mfma(D1, GiB, ro);           // X * Gi
    st_split(D2, u, ccol, h);
    f32x16 P = mm_mfma(GiB, D2, ro);           // Xc = Gi X Gi
    f32x16 L = logm_mfma(D1, D2, P, ro, ccol, h, dm);
    float sq = 0.f;
#pragma unroll
    for (int i = 0; i < 16; ++i) sq += L[i] * L[i];
    vacc += sq;
    float* g = Lout + m * 1024;
#pragma unroll
    for (int i = 0; i < 16; ++i) {
      const int row = (i & 3) + 8 * (i >> 2) + 4 * h;
      g[row * 32 + ccol] = L[i];
    }
  }
  vacc = wsum(vacc);
  if (lane == 0) atomicAdd(ws + WS_VAR + d, vacc);
}

__global__ __launch_bounds__(64) void k6_p(float* __restrict__ ws, int q, int D) {
  const int lane = threadIdx.x;
  if (lane < D) {
    const float cntf = ws[WS_CNT + lane];
    const float var = ws[WS_VAR + lane] / ((float)q * cntf);
    ws[WS_P + lane] = sqrtf(1.f / (var + 1e-5f));
  }
}

__global__ __launch_bounds__(128) void k7_out(const int* __restrict__ ds,
                                              const float* __restrict__ ws,
                                              const float* __restrict__ R,
                                              float* __restrict__ io, int q) {
  __shared__ unsigned RB[SMATU], BsB[SMATU];
  __shared__ unsigned DYN[2][2][SMATU];
  const int n = blockIdx.x, tid = threadIdx.x;
  const int w = tid >> 6, lane = tid & 63;
  const int ccol = lane & 31, h = lane >> 5;
  const int ro = ccol * SROW + h * 4;
  float dm[16];
#pragma unroll
  for (int i = 0; i < 16; ++i) {
    const int row = (i & 3) + 8 * (i >> 2) + 4 * h;
    dm[i] = (row == ccol) ? 1.f : 0.f;
  }
  const int d = ds[n];
  if (w == 0) x2l(R + d * 1024, RB, lane);
  else        x2l(ws + WS_BSQ + d * 1024, BsB, lane);
  __syncthreads();
  const float ph = 0.5f * ws[WS_P + d];
  // Taylor coeffs of exp(ph*L), deg 10, folded scale
  float coef[11];
  coef[0] = 1.f;
  coef[1] = ph;
  coef[2] = coef[1] * ph * 0.5f;
  coef[3] = coef[2] * ph * (1.f / 3.f);
  coef[4] = coef[3] * ph * 0.25f;
  coef[5] = coef[4] * ph * 0.2f;
  coef[6] = coef[5] * ph * (1.f / 6.f);
  coef[7] = coef[6] * ph * (1.f / 7.f);
  coef[8] = coef[7] * ph * 0.125f;
  coef[9] = coef[8] * ph * (1.f / 9.f);
  coef[10] = coef[9] * ph * 0.1f;
  unsigned* D1 = DYN[w][0]; unsigned* D2 = DYN[w][1];
  const int half = q >> 1;
#pragma unroll 1
  for (int j = 0; j < half; ++j) {
    const size_t m = (size_t)n * q + (size_t)w * half + j;
    x2l(io + m * 1024, D1, lane);              // L
    f32x16 H;
#pragma unroll
    for (int i = 0; i < 16; ++i) H[i] = 0.f;
    addID(H, coef[10], dm);
    st_split(D2, H, ccol, h);
#pragma unroll 1
    for (int kk = 9; kk >= 0; --kk) {          // H = L*H + c_kk I
      H = mm_mfma(D1, D2, ro);
      addID(H, coef[kk], dm);
      st_split(D2, H, ccol, h);
    }
    f32x16 t = mm_mfma(D2, D2, ro);            // Xp = H^2 = exp(p L)
    st_split(D1, t, ccol, h);
    t = mm_mfma(D1, RB, ro);                   // Xp * R^T
    st_split(D2, t, ccol, h);
    t = mm_mfma(RB, D2, ro);                   // Xr = R Xp R^T
    st_split(D1, t, ccol, h);
    t = mm_mfma(D1, BsB, ro);                  // Xr * Bs
    st_split(D2, t, ccol, h);
    t = mm_mfma(BsB, D2, ro);                  // out = Bs Xr Bs
    float* g = io + m * 1024;
#pragma unroll
    for (int i = 0; i < 16; ++i) {
      const int row = (i & 3) + 8 * (i >> 2) + 4 * h;
      g[row * 32 + ccol] = t[i];
    }
  }
}

// ------------------------------- launcher ----------------------------------

extern "C" void kernel_launch(void* const* d_in, const int* in_sizes, int n_in,
                              void* d_out, int out_size, void* d_ws, size_t ws_size,
                              hipStream_t stream) {
  const float* X  = (const float*)d_in[0];
  const int*   ds = (const int*)d_in[1];
  const float* R  = (const float*)d_in[2];
  const float* B  = (const float*)d_in[3];
  float* out = (float*)d_out;
  float* ws  = (float*)d_ws;
  const int N = in_sizes[1];
  const int q = in_sizes[0] / (N * 1024);
  const int D = in_sizes[2] / 1024;
  (void)n_in; (void)out_size; (void)ws_size;

  hipMemsetAsync(d_ws, 0, WS_ZERO * sizeof(float), stream);
  k1_g0sum  <<<dim3(N), dim3(64),  0, stream>>>(X, ds, ws, q);
  k2_g0funcs<<<dim3(D), dim3(128), 0, stream>>>(ws, ds, B, N, q);
  k3_gt     <<<dim3(N), dim3(128), 0, stream>>>(X, ds, ws, q);
  k4_mean   <<<dim3(D), dim3(64),  0, stream>>>(ws, q);
  k5_logxc  <<<dim3(N), dim3(128), 0, stream>>>(X, ds, ws, out, q);
  k6_p      <<<dim3(1), dim3(64),  0, stream>>>(ws, q, D);
  k7_out    <<<dim3(N), dim3(128), 0, stream>>>(ds, ws, R, out, q);
}